// Round 1
// baseline (11704.720 us; speedup 1.0000x reference)
//
#include <hip/hip_runtime.h>
#include <hip/hip_bf16.h>

// ---------------------------------------------------------------------------
// BiLSTM-CRF on MI355X.
// T=4096, E=1024, H=512 (per dir), 4H=2048, TAGSET=5, START=3, STOP=4.
// Structure:
//   gather_kernel : x_bf16[t][e] = bf16(embed[sentence[t]][e])
//   convw_kernel  : W_ih_{f,b} -> bf16
//   inith_kernel  : publish h0 into hcomm slot 0 (tag 0)
//   gemm_x_kernel : X{f,b} = x_bf16 @ W_ih^T + b   (MFMA 16x16x32 bf16)
//   lstm_kernel   : 32 WGs/dir, W_hh slice in VGPRs, h published per step as
//                   (tag<<16)|bf16 via relaxed agent atomics (data==flag)
//   feats_kernel  : feats[t][tag] = W_out . [hf[t], hb[t]] + b_out
//   viterbi_kernel: serial forward (1 wave), map-composition parallel backtrack
// ---------------------------------------------------------------------------

#define T_LEN 4096
#define EDIM  1024
#define HID   512
#define G4    2048   // 4*HID

typedef short short8 __attribute__((ext_vector_type(8)));
typedef float f32x4  __attribute__((ext_vector_type(4)));

__device__ __forceinline__ float bf16_to_f32(unsigned bits) {
  return __uint_as_float(bits << 16);
}
__device__ __forceinline__ unsigned bf16rne(float f) {
  unsigned u = __float_as_uint(f);
  return (u + 0x7fffu + ((u >> 16) & 1u)) >> 16;   // RNE, NaN not expected
}

// --------------------------- gather + convert ------------------------------
__global__ __launch_bounds__(256) void gather_kernel(
    const int* __restrict__ sent, const float* __restrict__ embed,
    unsigned short* __restrict__ xbf)
{
  const int t = blockIdx.x;
  const int tok = sent[t];
  const int e = threadIdx.x * 4;
  const float4 v = *(const float4*)(embed + (size_t)tok * EDIM + e);
  uint2 o;
  o.x = bf16rne(v.x) | (bf16rne(v.y) << 16);
  o.y = bf16rne(v.z) | (bf16rne(v.w) << 16);
  *(uint2*)(xbf + (size_t)t * EDIM + e) = o;
}

__global__ __launch_bounds__(256) void convw_kernel(
    const float* __restrict__ Wf, const float* __restrict__ Wb,
    unsigned short* __restrict__ of, unsigned short* __restrict__ ob)
{
  const float* src = blockIdx.z ? Wb : Wf;
  unsigned short* dst = blockIdx.z ? ob : of;
  const size_t idx = (size_t)blockIdx.x * 2048 + (size_t)threadIdx.x * 8;
  const float4 a = *(const float4*)(src + idx);
  const float4 b = *(const float4*)(src + idx + 4);
  uint4 o;
  o.x = bf16rne(a.x) | (bf16rne(a.y) << 16);
  o.y = bf16rne(a.z) | (bf16rne(a.w) << 16);
  o.z = bf16rne(b.x) | (bf16rne(b.y) << 16);
  o.w = bf16rne(b.z) | (bf16rne(b.w) << 16);
  *(uint4*)(dst + idx) = o;
}

__global__ __launch_bounds__(512) void inith_kernel(
    const float* __restrict__ h0, unsigned* __restrict__ hcF,
    unsigned* __restrict__ hcB)
{
  unsigned* hc = blockIdx.x ? hcB : hcF;
  const int j = threadIdx.x;
  hc[j] = bf16rne(h0[blockIdx.x * HID + j]);   // tag (high 16) = 0
}

// --------------------------- X = x @ W_ih^T + b ----------------------------
// 64x64 tile, 4 waves (each 32x32 via 2x2 MFMA 16x16x32), BK=32.
__global__ __launch_bounds__(256) void gemm_x_kernel(
    const unsigned short* __restrict__ xbf,
    const unsigned short* __restrict__ Wfb, const unsigned short* __restrict__ Wbb,
    const float* __restrict__ biasF, const float* __restrict__ biasB,
    float* __restrict__ Xf, float* __restrict__ Xb)
{
  const int zz = blockIdx.z;
  const unsigned short* Bp = zz ? Wbb : Wfb;
  const float* bias = zz ? biasB : biasF;
  float* C = zz ? Xb : Xf;
  const int n0 = blockIdx.x * 64;
  const int m0 = blockIdx.y * 64;
  __shared__ unsigned short As[64][40];   // stride 40 (80B): 16B-aligned, pads banks
  __shared__ unsigned short Bs[64][40];
  const int tid = threadIdx.x;
  const int wv = tid >> 6, lane = tid & 63;
  const int moff = (wv >> 1) * 32, noff = (wv & 1) * 32;
  const int lrow = tid >> 2, lseg = (tid & 3) * 8;
  const int fr = lane & 15;
  const int fk = (lane >> 4) * 8;
  f32x4 acc[2][2];
#pragma unroll
  for (int i = 0; i < 2; i++)
#pragma unroll
    for (int j = 0; j < 2; j++) acc[i][j] = (f32x4){0.f, 0.f, 0.f, 0.f};

  for (int k0 = 0; k0 < EDIM; k0 += 32) {
    const uint4 av = *(const uint4*)(xbf + (size_t)(m0 + lrow) * EDIM + k0 + lseg);
    const uint4 bv = *(const uint4*)(Bp  + (size_t)(n0 + lrow) * EDIM + k0 + lseg);
    *(uint4*)&As[lrow][lseg] = av;
    *(uint4*)&Bs[lrow][lseg] = bv;
    __syncthreads();
    short8 af[2], bg[2];
#pragma unroll
    for (int i = 0; i < 2; i++) af[i] = *(const short8*)&As[moff + i * 16 + fr][fk];
#pragma unroll
    for (int j = 0; j < 2; j++) bg[j] = *(const short8*)&Bs[noff + j * 16 + fr][fk];
#pragma unroll
    for (int i = 0; i < 2; i++)
#pragma unroll
      for (int j = 0; j < 2; j++)
        acc[i][j] = __builtin_amdgcn_mfma_f32_16x16x32_bf16(af[i], bg[j], acc[i][j], 0, 0, 0);
    __syncthreads();
  }
#pragma unroll
  for (int i = 0; i < 2; i++)
#pragma unroll
    for (int j = 0; j < 2; j++) {
      const int col = n0 + noff + j * 16 + fr;
      const float bv = bias[col];
#pragma unroll
      for (int r = 0; r < 4; r++) {
        const int row = m0 + moff + i * 16 + (lane >> 4) * 4 + r;
        C[(size_t)row * G4 + col] = acc[i][j][r] + bv;
      }
    }
}

// ------------------------------- recurrence --------------------------------
// 64 blocks x 512 threads. Block wg: dir = wg>>5, w = wg&31 owns h[w*16..w*16+16).
// Slice rows r in [0,64): gate = r>>4, jj = r&15, global row = gate*512+w*16+jj.
// Thread tid: g = tid>>5 (rows g*4..g*4+3), c = tid&31 (cols c*16..c*16+16).
__global__ __launch_bounds__(512) void lstm_kernel(
    const float* __restrict__ WhhF, const float* __restrict__ WhhB,
    const float* __restrict__ Xf, const float* __restrict__ Xb,
    const float* __restrict__ c0,
    unsigned* __restrict__ hcF, unsigned* __restrict__ hcB)
{
  const int wg = blockIdx.x;
  const int dir = wg >> 5;
  const int w = wg & 31;
  const float* Whh = dir ? WhhB : WhhF;
  const float* X   = dir ? Xb : Xf;
  unsigned* hcomm  = dir ? hcB : hcF;

  const int tid = threadIdx.x;
  const int g = tid >> 5;
  const int c = tid & 31;

  __shared__ float hl[HID];
  __shared__ float gl[64];
  __shared__ float xl[64];
  __shared__ float cl[16];

  float wreg[4][16];
#pragma unroll
  for (int rr = 0; rr < 4; ++rr) {
    const int r = g * 4 + rr;
    const int grow = (r >> 4) * HID + w * 16 + (r & 15);
#pragma unroll
    for (int kk = 0; kk < 16; ++kk)
      wreg[rr][kk] = Whh[(size_t)grow * HID + c * 16 + kk];
  }
  if (tid < 16) cl[tid] = c0[dir * HID + w * 16 + tid];
  __syncthreads();

  for (int s = 0; s < T_LEN; ++s) {
    // prefetch this step's input-projection rows (independent of the spin)
    float xv = 0.f;
    const int xrow = dir ? (T_LEN - 1 - s) : s;
    if (tid < 64)
      xv = X[(size_t)xrow * G4 + (tid >> 4) * HID + w * 16 + (tid & 15)];

    // spin until all 512 h elements of slot s carry tag s (data==flag)
    unsigned v;
    const unsigned want = (unsigned)s;
    for (;;) {
      v = __hip_atomic_load(&hcomm[(size_t)s * HID + tid],
                            __ATOMIC_RELAXED, __HIP_MEMORY_SCOPE_AGENT);
      if (__syncthreads_count((int)((v >> 16) == want)) == 512) break;
      __builtin_amdgcn_s_sleep(1);
    }
    hl[tid] = bf16_to_f32(v & 0xffffu);
    __syncthreads();

    // partial dot: rows g*4..g*4+3, cols c*16..c*16+16
    float p0 = 0.f, p1 = 0.f, p2 = 0.f, p3 = 0.f;
    const float4* hp = (const float4*)&hl[c * 16];
    float4 h4[4];
    h4[0] = hp[0]; h4[1] = hp[1]; h4[2] = hp[2]; h4[3] = hp[3];
    const float* hh = (const float*)h4;
#pragma unroll
    for (int kk = 0; kk < 16; ++kk) {
      const float hv = hh[kk];
      p0 += wreg[0][kk] * hv;
      p1 += wreg[1][kk] * hv;
      p2 += wreg[2][kk] * hv;
      p3 += wreg[3][kk] * hv;
    }
#pragma unroll
    for (int m = 1; m < 32; m <<= 1) {
      p0 += __shfl_xor(p0, m, 64);
      p1 += __shfl_xor(p1, m, 64);
      p2 += __shfl_xor(p2, m, 64);
      p3 += __shfl_xor(p3, m, 64);
    }
    if (c == 0) gl[g * 4 + 0] = p0;
    if (c == 1) gl[g * 4 + 1] = p1;
    if (c == 2) gl[g * 4 + 2] = p2;
    if (c == 3) gl[g * 4 + 3] = p3;
    if (tid < 64) xl[tid] = xv;
    __syncthreads();

    if (tid < 16) {
      const int jj = tid;
      const float gi = gl[jj]      + xl[jj];
      const float gf = gl[16 + jj] + xl[16 + jj];
      const float gg = gl[32 + jj] + xl[32 + jj];
      const float go = gl[48 + jj] + xl[48 + jj];
      const float ii = 1.f / (1.f + expf(-gi));
      const float ff = 1.f / (1.f + expf(-gf));
      const float tg = tanhf(gg);
      const float oo = 1.f / (1.f + expf(-go));
      const float cn = ff * cl[jj] + ii * tg;
      cl[jj] = cn;
      const float h = oo * tanhf(cn);
      const unsigned pk = ((unsigned)(s + 1) << 16) | bf16rne(h);
      __hip_atomic_store(&hcomm[(size_t)(s + 1) * HID + w * 16 + jj], pk,
                         __ATOMIC_RELAXED, __HIP_MEMORY_SCOPE_AGENT);
    }
    // next iteration's syncthreads_count is the barrier protecting hl/gl/xl reuse
  }
}

// ------------------------------- features ----------------------------------
__global__ __launch_bounds__(320) void feats_kernel(
    const unsigned* __restrict__ hcF, const unsigned* __restrict__ hcB,
    const float* __restrict__ Wout, const float* __restrict__ bout,
    float* __restrict__ feats)
{
  const int t = blockIdx.x;
  const int tag = threadIdx.x >> 6;   // 0..4, one wave per tag
  const int lane = threadIdx.x & 63;
  const unsigned* hf = hcF + (size_t)(t + 1) * HID;
  const unsigned* hb = hcB + (size_t)(T_LEN - t) * HID;
  float sum = 0.f;
  for (int e = lane; e < HID; e += 64) {
    sum += Wout[tag * 1024 + e]       * bf16_to_f32(hf[e] & 0xffffu);
    sum += Wout[tag * 1024 + 512 + e] * bf16_to_f32(hb[e] & 0xffffu);
  }
#pragma unroll
  for (int m = 1; m < 64; m <<= 1) sum += __shfl_xor(sum, m, 64);
  if (lane == 0) feats[t * 5 + tag] = sum + bout[tag];
}

// ------------------------------- Viterbi -----------------------------------
__device__ __forceinline__ unsigned map_compose(unsigned a, unsigned b) {
  // r[i] = a[b[i]]; 5 fields x 3 bits
  unsigned r = 0;
#pragma unroll
  for (int i = 0; i < 5; ++i) {
    const unsigned gi = (b >> (3 * i)) & 7u;
    r |= ((a >> (3 * gi)) & 7u) << (3 * i);
  }
  return r;
}

__global__ __launch_bounds__(64) void viterbi_kernel(
    const float* __restrict__ feats, const float* __restrict__ trans,
    float* __restrict__ out)
{
  __shared__ float fe[2][2560];            // 512 steps x 5, double buffered
  __shared__ unsigned char bpb[5][T_LEN];  // backpointers [tag][t]
  const int lane = threadIdx.x;
  const int n = lane >> 3, p = lane & 7;
  const bool act = (n < 5) && (p < 5);
  const int nn = (n < 5) ? n : 0;
  const float tr = act ? trans[n * 5 + p] : -3.0e38f;
  float fvp = (p == 3) ? 0.f : -10000.f;   // fv[p], START=3

  for (int i = lane; i < 2560; i += 64) fe[0][i] = feats[i];
  __syncthreads();

  for (int ch = 0; ch < 8; ++ch) {
    const int buf = ch & 1;
    float pf[40];
    if (ch < 7) {
#pragma unroll
      for (int i = 0; i < 40; ++i)
        pf[i] = feats[(ch + 1) * 2560 + i * 64 + lane];
    }
    for (int tt = 0; tt < 512; ++tt) {
      const int t = ch * 512 + tt;
      float s = act ? (fvp + tr) : -3.0e38f;
      float bm = s; int bp_ = p;
#pragma unroll
      for (int d = 1; d < 8; d <<= 1) {
        const float os = __shfl_xor(bm, d, 64);
        const int   op = __shfl_xor(bp_, d, 64);
        if (os > bm || (os == bm && op < bp_)) { bm = os; bp_ = op; }
      }
      const float fvn = bm + fe[buf][tt * 5 + nn];
      if (p == 0 && n < 5) bpb[n][t] = (unsigned char)bp_;
      fvp = __shfl(fvn, p * 8, 64);   // new fv[p] from group p
    }
    __syncthreads();
    if (ch < 7) {
#pragma unroll
      for (int i = 0; i < 40; ++i) fe[buf ^ 1][i * 64 + lane] = pf[i];
    }
    __syncthreads();
  }

  // terminal: lanes 0..4 hold fv[lane]
  float tv = (lane < 5) ? (fvp + trans[4 * 5 + lane]) : -3.0e38f;
  int bl = lane;
#pragma unroll
  for (int d = 1; d < 8; d <<= 1) {
    const float ov = __shfl_xor(tv, d, 64);
    const int   ol = __shfl_xor(bl, d, 64);
    if (ov > tv || (ov == tv && ol < bl)) { tv = ov; bl = ol; }
  }
  const float score = __shfl(tv, 0, 64);
  const int best = __shfl(bl, 0, 64);
  if (lane == 0) out[0] = score;

  // parallel backtrack: lane L covers t in [L*64, L*64+63]
  const unsigned IDENT = 0u | (1u << 3) | (2u << 6) | (3u << 9) | (4u << 12);
  const int lo = lane * 64;
  unsigned msave[64];
  unsigned comp = IDENT;
#pragma unroll
  for (int tt = 0; tt < 64; ++tt) {
    const int t = lo + tt;
    unsigned mt;
    if (t == 0) mt = IDENT;               // M_0 unused
    else
      mt = (unsigned)bpb[0][t] | ((unsigned)bpb[1][t] << 3) |
           ((unsigned)bpb[2][t] << 6) | ((unsigned)bpb[3][t] << 9) |
           ((unsigned)bpb[4][t] << 12);
    msave[tt] = mt;
    comp = map_compose(comp, mt);         // comp = M_lo o ... o M_t
  }
  // inclusive suffix scan: inc_L = C_L o C_{L+1} o ... o C_63
  unsigned inc = comp;
#pragma unroll
  for (int d = 1; d < 64; d <<= 1) {
    const unsigned other = __shfl_down(inc, d, 64);
    const unsigned comb = map_compose(inc, other);
    if (lane + d < 64) inc = comb;
  }
  unsigned exc = __shfl_down(inc, 1, 64); // E_L = inc_{L+1}
  if (lane == 63) exc = IDENT;

  int y = (int)((exc >> (3 * best)) & 7u);  // path[hi_L]
  out[1 + lo + 63] = (float)y;
#pragma unroll
  for (int tt = 63; tt >= 0; --tt) {
    const int t = lo + tt;
    if (t == 0) break;
    y = (int)((msave[tt] >> (3 * y)) & 7u);  // path[t-1] = M_t(path[t])
    out[1 + t - 1] = (float)y;
  }
}

// ------------------------------- launcher ----------------------------------
extern "C" void kernel_launch(void* const* d_in, const int* in_sizes, int n_in,
                              void* d_out, int out_size, void* d_ws, size_t ws_size,
                              hipStream_t stream) {
  const int*   sent   = (const int*)d_in[0];
  const float* embed  = (const float*)d_in[1];
  const float* W_ih_f = (const float*)d_in[2];
  const float* W_hh_f = (const float*)d_in[3];
  const float* b_f    = (const float*)d_in[4];
  const float* W_ih_b = (const float*)d_in[5];
  const float* W_hh_b = (const float*)d_in[6];
  const float* b_b    = (const float*)d_in[7];
  const float* h0     = (const float*)d_in[8];
  const float* c0     = (const float*)d_in[9];
  const float* W_out  = (const float*)d_in[10];
  const float* b_out  = (const float*)d_in[11];
  const float* trans  = (const float*)d_in[12];

  char* ws = (char*)d_ws;
  float*          Xf    = (float*)(ws + 0);              // 33,554,432 B
  float*          Xb    = (float*)(ws + 33554432);       // 33,554,432 B
  unsigned short* xbf   = (unsigned short*)(ws + 67108864);   // 8,388,608 B
  unsigned short* Wfb   = (unsigned short*)(ws + 75497472);   // 4,194,304 B
  unsigned short* Wbb   = (unsigned short*)(ws + 79691776);   // 4,194,304 B
  unsigned*       hcF   = (unsigned*)(ws + 83886080);    // 8,390,656 B
  unsigned*       hcB   = (unsigned*)(ws + 92276736);    // 8,390,656 B
  float*          feats = (float*)(ws + 100667392);      // 81,920 B
  float*          out   = (float*)d_out;

  gather_kernel<<<T_LEN, 256, 0, stream>>>(sent, embed, xbf);
  convw_kernel<<<dim3(1024, 1, 2), 256, 0, stream>>>(W_ih_f, W_ih_b, Wfb, Wbb);
  inith_kernel<<<2, 512, 0, stream>>>(h0, hcF, hcB);
  gemm_x_kernel<<<dim3(32, 64, 2), 256, 0, stream>>>(xbf, Wfb, Wbb, b_f, b_b, Xf, Xb);
  lstm_kernel<<<64, 512, 0, stream>>>(W_hh_f, W_hh_b, Xf, Xb, c0, hcF, hcB);
  feats_kernel<<<T_LEN, 320, 0, stream>>>(hcF, hcB, W_out, b_out, feats);
  viterbi_kernel<<<1, 64, 0, stream>>>(feats, trans, out);
}